// Round 1
// baseline (159.854 us; speedup 1.0000x reference)
//
#include <hip/hip_runtime.h>

// ---------------- types ----------------
typedef __attribute__((ext_vector_type(8))) short bf16x8;   // 8 bf16 in 4 VGPRs
typedef __attribute__((ext_vector_type(4))) float f32x4;
typedef __attribute__((ext_vector_type(4))) unsigned short us4;

#define K_DIM 2048
#define QK_N  320     // 256 q cols + 64 k cols
#define SEQ   4096

__device__ __forceinline__ unsigned short f2bf(float f) {
    unsigned int u = __builtin_bit_cast(unsigned int, f);
    u += 0x7FFFu + ((u >> 16) & 1u);      // round-to-nearest-even
    return (unsigned short)(u >> 16);
}

// ---------------- fp32 -> bf16 convert, x4 vectorized ----------------
__global__ void cvt_f32_bf16(const float* __restrict__ in,
                             unsigned short* __restrict__ out, int n4) {
    int i = blockIdx.x * blockDim.x + threadIdx.x;
    if (i >= n4) return;
    float4 v = reinterpret_cast<const float4*>(in)[i];
    us4 o;
    o[0] = f2bf(v.x); o[1] = f2bf(v.y); o[2] = f2bf(v.z); o[3] = f2bf(v.w);
    reinterpret_cast<us4*>(out)[i] = o;
}

// ---------------- projection GEMM: C[8192][320] = A[8192][2048] * W[320][2048]^T ----------------
// block = 256 threads = 4 waves (2x2). block tile 128x64, wave tile 64x32.
__global__ __launch_bounds__(256) void proj_gemm(
    const unsigned short* __restrict__ A,
    const unsigned short* __restrict__ W,
    unsigned short* __restrict__ C)
{
    const int lane = threadIdx.x & 63;
    const int wid  = threadIdx.x >> 6;
    const int row0 = blockIdx.y * 128 + (wid >> 1) * 64;
    const int col0 = blockIdx.x * 64  + (wid & 1) * 32;

    const int lr = lane & 15;          // fragment row (A) / col (B)
    const int lk = (lane >> 4) * 8;    // fragment k offset

    f32x4 acc[4][2];
#pragma unroll
    for (int i = 0; i < 4; ++i)
#pragma unroll
        for (int j = 0; j < 2; ++j) acc[i][j] = (f32x4)0.f;

    const unsigned short* ap = A + (size_t)(row0 + lr) * K_DIM + lk;
    const unsigned short* bp = W + (size_t)(col0 + lr) * K_DIM + lk;

    for (int k0 = 0; k0 < K_DIM; k0 += 32) {
        bf16x8 a[4], b[2];
#pragma unroll
        for (int i = 0; i < 4; ++i)
            a[i] = *reinterpret_cast<const bf16x8*>(ap + (size_t)i * 16 * K_DIM + k0);
#pragma unroll
        for (int j = 0; j < 2; ++j)
            b[j] = *reinterpret_cast<const bf16x8*>(bp + (size_t)j * 16 * K_DIM + k0);
#pragma unroll
        for (int i = 0; i < 4; ++i)
#pragma unroll
            for (int j = 0; j < 2; ++j)
                acc[i][j] = __builtin_amdgcn_mfma_f32_16x16x32_bf16(a[i], b[j], acc[i][j], 0, 0, 0);
    }

    const int orow = (lane >> 4) * 4;
#pragma unroll
    for (int i = 0; i < 4; ++i)
#pragma unroll
        for (int j = 0; j < 2; ++j)
#pragma unroll
            for (int r = 0; r < 4; ++r)
                C[(size_t)(row0 + i * 16 + orow + r) * QK_N + col0 + j * 16 + lr] =
                    f2bf(acc[i][j][r]);
}

// ---------------- scores: I[b,t,s] = sum_h w[h]*relu(Q_h K^T) ----------------
// grid (32,32,2); block 256 = 4 waves (2x2). block tile 128x128, wave tile 64x64.
__global__ __launch_bounds__(256) void scores_kernel(
    const unsigned short* __restrict__ QK,   // [B][4096][320] bf16
    const float* __restrict__ w,             // [4]
    float* __restrict__ out)                 // [B][4096][4096] fp32
{
    const int lane = threadIdx.x & 63;
    const int wid  = threadIdx.x >> 6;
    const int b  = blockIdx.z;
    const int t0 = blockIdx.y * 128 + (wid >> 1) * 64;
    const int s0 = blockIdx.x * 128 + (wid & 1) * 64;

    const int lr = lane & 15;
    const int lk = (lane >> 4) * 8;

    const unsigned short* Qb = QK + (size_t)b * SEQ * QK_N;
    const unsigned short* Kb = Qb + 256;

    float wv0 = w[0], wv1 = w[1], wv2 = w[2], wv3 = w[3];
    float wv[4] = { wv0, wv1, wv2, wv3 };

    f32x4 fin[4][4];
#pragma unroll
    for (int i = 0; i < 4; ++i)
#pragma unroll
        for (int j = 0; j < 4; ++j) fin[i][j] = (f32x4)0.f;

    const unsigned short* qp = Qb + (size_t)(t0 + lr) * QK_N + lk;
    const unsigned short* kp = Kb + (size_t)(s0 + lr) * QK_N + lk;

#pragma unroll
    for (int h = 0; h < 4; ++h) {
        f32x4 acc[4][4];
#pragma unroll
        for (int i = 0; i < 4; ++i)
#pragma unroll
            for (int j = 0; j < 4; ++j) acc[i][j] = (f32x4)0.f;

#pragma unroll
        for (int ks = 0; ks < 2; ++ks) {
            bf16x8 a[4], bb[4];
#pragma unroll
            for (int i = 0; i < 4; ++i)
                a[i] = *reinterpret_cast<const bf16x8*>(
                    qp + (size_t)i * 16 * QK_N + h * 64 + ks * 32);
#pragma unroll
            for (int j = 0; j < 4; ++j)
                bb[j] = *reinterpret_cast<const bf16x8*>(
                    kp + (size_t)j * 16 * QK_N + ks * 32);
#pragma unroll
            for (int i = 0; i < 4; ++i)
#pragma unroll
                for (int j = 0; j < 4; ++j)
                    acc[i][j] = __builtin_amdgcn_mfma_f32_16x16x32_bf16(a[i], bb[j], acc[i][j], 0, 0, 0);
        }
#pragma unroll
        for (int i = 0; i < 4; ++i)
#pragma unroll
            for (int j = 0; j < 4; ++j)
#pragma unroll
                for (int r = 0; r < 4; ++r)
                    fin[i][j][r] += wv[h] * fmaxf(acc[i][j][r], 0.f);
    }

    const int orow = (lane >> 4) * 4;
    float* ob = out + (size_t)b * SEQ * SEQ;
#pragma unroll
    for (int i = 0; i < 4; ++i)
#pragma unroll
        for (int j = 0; j < 4; ++j)
#pragma unroll
            for (int r = 0; r < 4; ++r)
                ob[(size_t)(t0 + i * 16 + orow + r) * SEQ + s0 + j * 16 + lr] =
                    fin[i][j][r];
}

// ---------------- launch ----------------
extern "C" void kernel_launch(void* const* d_in, const int* in_sizes, int n_in,
                              void* d_out, int out_size, void* d_ws, size_t ws_size,
                              hipStream_t stream) {
    const float* h  = (const float*)d_in[0];   // [2,4096,2048]
    const float* Wq = (const float*)d_in[1];   // [256,2048]
    const float* Wk = (const float*)d_in[2];   // [64,2048]
    const float* w  = (const float*)d_in[3];   // [4]
    float* out = (float*)d_out;                // [2,4096,4096]

    unsigned short* h_bf = (unsigned short*)d_ws;            // 8192*2048 bf16
    unsigned short* W_bf = h_bf + (size_t)8192 * 2048;       // 320*2048 bf16 (Wq rows 0..255, Wk rows 256..319)
    unsigned short* QKb  = W_bf + (size_t)320 * 2048;        // 8192*320 bf16

    int n4h = 8192 * 2048 / 4;
    cvt_f32_bf16<<<(n4h + 255) / 256, 256, 0, stream>>>(h, h_bf, n4h);
    int n4q = 256 * 2048 / 4;
    cvt_f32_bf16<<<(n4q + 255) / 256, 256, 0, stream>>>(Wq, W_bf, n4q);
    int n4k = 64 * 2048 / 4;
    cvt_f32_bf16<<<(n4k + 255) / 256, 256, 0, stream>>>(Wk, W_bf + (size_t)256 * 2048, n4k);

    proj_gemm<<<dim3(5, 64), 256, 0, stream>>>(h_bf, W_bf, QKb);
    scores_kernel<<<dim3(32, 32, 2), 256, 0, stream>>>(QKb, w, out);
}

// Round 2
// 119.432 us; speedup vs baseline: 1.3384x; 1.3384x over previous
//
#include <hip/hip_runtime.h>

// ---------------- types ----------------
typedef __attribute__((ext_vector_type(8))) short bf16x8;   // 8 bf16 in 4 VGPRs
typedef __attribute__((ext_vector_type(4))) float f32x4;
typedef __attribute__((ext_vector_type(8))) unsigned short us8;
typedef __attribute__((ext_vector_type(4))) unsigned short us4;

#define K_DIM 2048
#define QK_N  320     // 256 q cols + 64 k cols
#define SEQ   4096
#define BK    32
#define NCHUNK (K_DIM / BK)            // 64
#define CHUNK_BYTES (QK_N * BK * 2)    // 20480 (20 KB)

__device__ __forceinline__ unsigned short f2bf(float f) {
    unsigned int u = __builtin_bit_cast(unsigned int, f);
    u += 0x7FFFu + ((u >> 16) & 1u);      // round-to-nearest-even
    return (unsigned short)(u >> 16);
}

__device__ __forceinline__ void gld_lds16(const void* g, void* l) {
    __builtin_amdgcn_global_load_lds(
        (const __attribute__((address_space(1))) void*)g,
        (__attribute__((address_space(3))) void*)l,
        16, 0, 0);
}

// ---------------- W convert + re-layout ----------------
// ws layout: [NCHUNK][BK/8 units][320 cols][16B]  (unit-major so that
// ds_read_b128 of 16 consecutive cols at fixed k-unit is bank-conflict-free,
// and global_load_lds staging is a linear byte copy)
__global__ void cvt_w_swz(const float* __restrict__ Wq,
                          const float* __restrict__ Wk,
                          unsigned short* __restrict__ ws) {
    int id = blockIdx.x * 256 + threadIdx.x;   // 320*256 ids
    int c  = id >> 8;                          // 0..319 (output col)
    int k8 = id & 255;                         // 8-elem k group
    int k0 = k8 * 8;
    const float* src = (c < 256) ? (Wq + (size_t)c * K_DIM + k0)
                                 : (Wk + (size_t)(c - 256) * K_DIM + k0);
    float4 v0 = *reinterpret_cast<const float4*>(src);
    float4 v1 = *reinterpret_cast<const float4*>(src + 4);
    us8 o;
    o[0] = f2bf(v0.x); o[1] = f2bf(v0.y); o[2] = f2bf(v0.z); o[3] = f2bf(v0.w);
    o[4] = f2bf(v1.x); o[5] = f2bf(v1.y); o[6] = f2bf(v1.z); o[7] = f2bf(v1.w);
    int kc = k0 / BK;            // chunk index
    int u  = (k0 % BK) >> 3;     // k-unit within chunk (0..3)
    size_t byteoff = (size_t)kc * CHUNK_BYTES + ((size_t)(u * QK_N + c) * 16);
    *reinterpret_cast<us8*>((char*)ws + byteoff) = o;
}

// ---------------- projection GEMM: C[8192][320] = h[8192][2048](fp32) * W^T ----------------
// grid 256 blocks, 512 threads = 8 waves (2 row-groups x 4 col-groups).
// block tile 32x320; wave tile 16x80. W staged in LDS (dbuf), h read fp32 + cvt in-reg.
__global__ __launch_bounds__(512) void proj_gemm(
    const float* __restrict__ A,            // h fp32 [8192][2048]
    const unsigned short* __restrict__ Wsz, // re-laid-out W chunks
    unsigned short* __restrict__ C)         // [8192][320] bf16
{
    __shared__ unsigned short Bs[2][CHUNK_BYTES / 2];   // 2 x 20KB

    const int tid  = threadIdx.x;
    const int lane = tid & 63;
    const int wid  = tid >> 6;          // 0..7
    const int rg   = wid >> 2;          // 0..1
    const int cg   = wid & 3;           // 0..3
    const int row0 = blockIdx.x * 32 + rg * 16;
    const int col0 = cg * 80;
    const int lr   = lane & 15;
    const int lg   = lane >> 4;         // 0..3

    const float* ap = A + (size_t)(row0 + lr) * K_DIM + lg * 8;

    f32x4 acc[5];
#pragma unroll
    for (int j = 0; j < 5; ++j) acc[j] = (f32x4)0.f;

    // stage chunk kc into LDS buf (linear copy, all 8 waves cooperate)
    auto stage = [&](int kc, int buf) {
        const char* src = (const char*)Wsz + (size_t)kc * CHUNK_BYTES;
        char* dst = (char*)&Bs[buf][0];
#pragma unroll
        for (int n = 0; n < 3; ++n) {
            int chunk = wid + n * 8;
            if (chunk < 20)
                gld_lds16(src + chunk * 1024 + lane * 16, dst + chunk * 1024);
        }
    };

    auto compute = [&](int buf, float4 x, float4 y) {
        bf16x8 a;
        a[0] = (short)f2bf(x.x); a[1] = (short)f2bf(x.y);
        a[2] = (short)f2bf(x.z); a[3] = (short)f2bf(x.w);
        a[4] = (short)f2bf(y.x); a[5] = (short)f2bf(y.y);
        a[6] = (short)f2bf(y.z); a[7] = (short)f2bf(y.w);
        const char* base = (const char*)&Bs[buf][0] + (size_t)lg * (QK_N * 16);
#pragma unroll
        for (int j = 0; j < 5; ++j) {
            int c = col0 + j * 16 + lr;
            bf16x8 b = *reinterpret_cast<const bf16x8*>(base + (size_t)c * 16);
            acc[j] = __builtin_amdgcn_mfma_f32_16x16x32_bf16(a, b, acc[j], 0, 0, 0);
        }
    };

    // prologue
    stage(0, 0);
    float4 arA0 = *reinterpret_cast<const float4*>(ap);
    float4 arA1 = *reinterpret_cast<const float4*>(ap + 4);
    float4 arB0, arB1;
    __syncthreads();

    for (int kc = 0; kc < NCHUNK; kc += 2) {
        // even iter: read buf0 / arA; prefetch kc+1 into buf1 / arB
        stage(kc + 1, 1);
        arB0 = *reinterpret_cast<const float4*>(ap + (size_t)(kc + 1) * BK);
        arB1 = *reinterpret_cast<const float4*>(ap + (size_t)(kc + 1) * BK + 4);
        compute(0, arA0, arA1);
        __syncthreads();
        // odd iter: read buf1 / arB; prefetch kc+2 into buf0 / arA
        if (kc + 2 < NCHUNK) {
            stage(kc + 2, 0);
            arA0 = *reinterpret_cast<const float4*>(ap + (size_t)(kc + 2) * BK);
            arA1 = *reinterpret_cast<const float4*>(ap + (size_t)(kc + 2) * BK + 4);
        }
        compute(1, arB0, arB1);
        __syncthreads();
    }

    // epilogue: C layout col=lane&15, row=(lane>>4)*4+r
#pragma unroll
    for (int j = 0; j < 5; ++j)
#pragma unroll
        for (int r = 0; r < 4; ++r)
            C[(size_t)(row0 + lg * 4 + r) * QK_N + col0 + j * 16 + lr] =
                f2bf(acc[j][r]);
}

// ---------------- scores: I[b,t,s] = sum_h w[h]*relu(Q_h K^T) ----------------
// grid (32,32,2); block 256 = 4 waves (2x2). block tile 128x128, wave tile 64x64.
__global__ __launch_bounds__(256) void scores_kernel(
    const unsigned short* __restrict__ QK,   // [B][4096][320] bf16
    const float* __restrict__ w,             // [4]
    float* __restrict__ out)                 // [B][4096][4096] fp32
{
    const int lane = threadIdx.x & 63;
    const int wid  = threadIdx.x >> 6;
    const int b  = blockIdx.z;
    const int t0 = blockIdx.y * 128 + (wid >> 1) * 64;
    const int s0 = blockIdx.x * 128 + (wid & 1) * 64;

    const int lr = lane & 15;
    const int lk = (lane >> 4) * 8;

    const unsigned short* Qb = QK + (size_t)b * SEQ * QK_N;
    const unsigned short* Kb = Qb + 256;

    float wv[4] = { w[0], w[1], w[2], w[3] };

    f32x4 fin[4][4];
#pragma unroll
    for (int i = 0; i < 4; ++i)
#pragma unroll
        for (int j = 0; j < 4; ++j) fin[i][j] = (f32x4)0.f;

    const unsigned short* qp = Qb + (size_t)(t0 + lr) * QK_N + lk;
    const unsigned short* kp = Kb + (size_t)(s0 + lr) * QK_N + lk;

#pragma unroll
    for (int h = 0; h < 4; ++h) {
        f32x4 acc[4][4];
#pragma unroll
        for (int i = 0; i < 4; ++i)
#pragma unroll
            for (int j = 0; j < 4; ++j) acc[i][j] = (f32x4)0.f;

#pragma unroll
        for (int ks = 0; ks < 2; ++ks) {
            bf16x8 a[4], bb[4];
#pragma unroll
            for (int i = 0; i < 4; ++i)
                a[i] = *reinterpret_cast<const bf16x8*>(
                    qp + (size_t)i * 16 * QK_N + h * 64 + ks * 32);
#pragma unroll
            for (int j = 0; j < 4; ++j)
                bb[j] = *reinterpret_cast<const bf16x8*>(
                    kp + (size_t)j * 16 * QK_N + ks * 32);
#pragma unroll
            for (int i = 0; i < 4; ++i)
#pragma unroll
                for (int j = 0; j < 4; ++j)
                    acc[i][j] = __builtin_amdgcn_mfma_f32_16x16x32_bf16(a[i], bb[j], acc[i][j], 0, 0, 0);
        }
#pragma unroll
        for (int i = 0; i < 4; ++i)
#pragma unroll
            for (int j = 0; j < 4; ++j)
#pragma unroll
                for (int r = 0; r < 4; ++r)
                    fin[i][j][r] += wv[h] * fmaxf(acc[i][j][r], 0.f);
    }

    const int orow = (lane >> 4) * 4;
    float* ob = out + (size_t)b * SEQ * SEQ;
#pragma unroll
    for (int i = 0; i < 4; ++i)
#pragma unroll
        for (int j = 0; j < 4; ++j)
#pragma unroll
            for (int r = 0; r < 4; ++r)
                ob[(size_t)(t0 + i * 16 + orow + r) * SEQ + s0 + j * 16 + lr] =
                    fin[i][j][r];
}

// ---------------- launch ----------------
extern "C" void kernel_launch(void* const* d_in, const int* in_sizes, int n_in,
                              void* d_out, int out_size, void* d_ws, size_t ws_size,
                              hipStream_t stream) {
    const float* h  = (const float*)d_in[0];   // [2,4096,2048]
    const float* Wq = (const float*)d_in[1];   // [256,2048]
    const float* Wk = (const float*)d_in[2];   // [64,2048]
    const float* w  = (const float*)d_in[3];   // [4]
    float* out = (float*)d_out;                // [2,4096,4096]

    unsigned short* W_swz = (unsigned short*)d_ws;                 // 64 chunks x 20KB = 1.25MB
    unsigned short* QKb   = (unsigned short*)((char*)d_ws + (size_t)NCHUNK * CHUNK_BYTES);

    cvt_w_swz<<<320, 256, 0, stream>>>(Wq, Wk, W_swz);
    proj_gemm<<<256, 512, 0, stream>>>(h, W_swz, QKb);
    scores_kernel<<<dim3(32, 32, 2), 256, 0, stream>>>(QKb, w, out);
}

// Round 3
// 113.268 us; speedup vs baseline: 1.4113x; 1.0544x over previous
//
#include <hip/hip_runtime.h>

// ---------------- types ----------------
typedef __attribute__((ext_vector_type(8))) short bf16x8;   // 8 bf16 in 4 VGPRs
typedef __attribute__((ext_vector_type(4))) float f32x4;
typedef __attribute__((ext_vector_type(8))) unsigned short us8;

#define K_DIM 2048
#define QK_N  320     // 256 q cols + 64 k cols
#define SEQ   4096
#define BK    64
#define NCHUNK (K_DIM / BK)            // 32
#define CHUNK_BYTES (QK_N * BK * 2)    // 40960 (40 KB)

__device__ __forceinline__ unsigned short f2bf(float f) {
    unsigned int u = __builtin_bit_cast(unsigned int, f);
    u += 0x7FFFu + ((u >> 16) & 1u);      // round-to-nearest-even
    return (unsigned short)(u >> 16);
}

__device__ __forceinline__ void gld_lds16(const void* g, void* l) {
    __builtin_amdgcn_global_load_lds(
        (const __attribute__((address_space(1))) void*)g,
        (__attribute__((address_space(3))) void*)l,
        16, 0, 0);
}

// ---------------- W convert + re-layout ----------------
// ws layout: [NCHUNK][8 k-units][320 cols][16B]  (unit-major: ds_read_b128 of
// 16 consecutive cols at fixed k-unit is conflict-free; global_load_lds
// staging is a linear byte copy)
__global__ void cvt_w_swz(const float* __restrict__ Wq,
                          const float* __restrict__ Wk,
                          unsigned short* __restrict__ ws) {
    int id = blockIdx.x * 256 + threadIdx.x;   // 320*256 ids
    int c  = id >> 8;                          // 0..319 (output col)
    int k8 = id & 255;                         // 8-elem k group
    int k0 = k8 * 8;
    const float* src = (c < 256) ? (Wq + (size_t)c * K_DIM + k0)
                                 : (Wk + (size_t)(c - 256) * K_DIM + k0);
    float4 v0 = *reinterpret_cast<const float4*>(src);
    float4 v1 = *reinterpret_cast<const float4*>(src + 4);
    us8 o;
    o[0] = f2bf(v0.x); o[1] = f2bf(v0.y); o[2] = f2bf(v0.z); o[3] = f2bf(v0.w);
    o[4] = f2bf(v1.x); o[5] = f2bf(v1.y); o[6] = f2bf(v1.z); o[7] = f2bf(v1.w);
    int kc = k0 / BK;            // chunk index 0..31
    int u  = (k0 % BK) >> 3;     // k-unit within chunk (0..7)
    size_t byteoff = (size_t)kc * CHUNK_BYTES + ((size_t)(u * QK_N + c) * 16);
    *reinterpret_cast<us8*>((char*)ws + byteoff) = o;
}

// ---------------- projection GEMM: C[8192][320] = h[8192][2048](fp32) * W^T ----------------
// grid 256 blocks x 512 threads (8 waves: 2 row-groups x 4 col-groups).
// block tile 32x320; wave tile 16x80. W double-buffered in LDS via
// global_load_lds; counted-vmcnt barriers keep A prefetch in flight.
__global__ __launch_bounds__(512, 2) void proj_gemm(
    const float* __restrict__ A,            // h fp32 [8192][2048]
    const unsigned short* __restrict__ Wsz, // re-laid-out W chunks
    unsigned short* __restrict__ C)         // [8192][320] bf16
{
    __shared__ unsigned short Bs[2][CHUNK_BYTES / 2];   // 2 x 40KB

    const int tid  = threadIdx.x;
    const int lane = tid & 63;
    const int wid  = tid >> 6;          // 0..7
    const int rg   = wid >> 2;          // 0..1
    const int cg   = wid & 3;           // 0..3
    const int row0 = blockIdx.x * 32 + rg * 16;
    const int col0 = cg * 80;
    const int lr   = lane & 15;
    const int lg   = lane >> 4;         // 0..3

    const float* ap = A + (size_t)(row0 + lr) * K_DIM + lg * 8;

    f32x4 acc[5];
#pragma unroll
    for (int j = 0; j < 5; ++j) acc[j] = (f32x4)0.f;

    // stage chunk kc into LDS buf: 5 x 1KB per wave, linear copy
    const char* wsrc = (const char*)Wsz;
    auto stage = [&](int kc, int buf) {
        const char* src = wsrc + (size_t)kc * CHUNK_BYTES + wid * 5120 + lane * 16;
        char* dst = (char*)&Bs[buf][0] + wid * 5120 + lane * 16;
#pragma unroll
        for (int i = 0; i < 5; ++i)
            gld_lds16(src + i * 1024, dst + i * 1024);
    };

    auto loadA = [&](int kc, float4& f0, float4& f1, float4& f2, float4& f3) {
        const float* p = ap + (size_t)kc * BK;
        f0 = *reinterpret_cast<const float4*>(p);
        f1 = *reinterpret_cast<const float4*>(p + 4);
        f2 = *reinterpret_cast<const float4*>(p + 32);
        f3 = *reinterpret_cast<const float4*>(p + 36);
    };

    auto compute = [&](int buf, float4 f0, float4 f1, float4 f2, float4 f3) {
        const char* base = (const char*)&Bs[buf][0];
#pragma unroll
        for (int ks = 0; ks < 2; ++ks) {
            bf16x8 a;
            float4 x = ks ? f2 : f0, y = ks ? f3 : f1;
            a[0] = (short)f2bf(x.x); a[1] = (short)f2bf(x.y);
            a[2] = (short)f2bf(x.z); a[3] = (short)f2bf(x.w);
            a[4] = (short)f2bf(y.x); a[5] = (short)f2bf(y.y);
            a[6] = (short)f2bf(y.z); a[7] = (short)f2bf(y.w);
            const char* ub = base + (size_t)(ks * 4 + lg) * (QK_N * 16);
#pragma unroll
            for (int j = 0; j < 5; ++j) {
                int c = col0 + j * 16 + lr;
                bf16x8 b = *reinterpret_cast<const bf16x8*>(ub + (size_t)c * 16);
                acc[j] = __builtin_amdgcn_mfma_f32_16x16x32_bf16(a, b, acc[j], 0, 0, 0);
            }
        }
    };

#define WAIT_BAR() do { \
        asm volatile("s_waitcnt vmcnt(4) lgkmcnt(0)" ::: "memory"); \
        __builtin_amdgcn_s_barrier(); \
    } while (0)

    // prologue: stage chunk 0, prefetch A(0); A loads may stay in flight
    float4 a0, a1, a2, a3, b0, b1, b2, b3;
    stage(0, 0);
    loadA(0, a0, a1, a2, a3);
    WAIT_BAR();

    for (int kc = 0; kc < NCHUNK; kc += 2) {
        // even: compute buf0/A(kc); prefetch kc+1 -> buf1/B-regs
        stage(kc + 1, 1);
        loadA(kc + 1, b0, b1, b2, b3);
        compute(0, a0, a1, a2, a3);
        WAIT_BAR();
        // odd: compute buf1/A(kc+1); prefetch kc+2 -> buf0/A-regs
        if (kc + 2 < NCHUNK) {
            stage(kc + 2, 0);
            loadA(kc + 2, a0, a1, a2, a3);
        }
        compute(1, b0, b1, b2, b3);
        WAIT_BAR();
    }
#undef WAIT_BAR

    // epilogue: C layout col=lane&15, row=(lane>>4)*4+r
#pragma unroll
    for (int j = 0; j < 5; ++j)
#pragma unroll
        for (int r = 0; r < 4; ++r)
            C[(size_t)(row0 + lg * 4 + r) * QK_N + col0 + j * 16 + lr] =
                f2bf(acc[j][r]);
}

// ---------------- scores: I[b,t,s] = sum_h w[h]*relu(Q_h K^T) ----------------
// grid (32,32,2); block 256 = 4 waves (2x2). block tile 128x128, wave tile 64x64.
__global__ __launch_bounds__(256) void scores_kernel(
    const unsigned short* __restrict__ QK,   // [B][4096][320] bf16
    const float* __restrict__ w,             // [4]
    float* __restrict__ out)                 // [B][4096][4096] fp32
{
    const int lane = threadIdx.x & 63;
    const int wid  = threadIdx.x >> 6;
    const int b  = blockIdx.z;
    const int t0 = blockIdx.y * 128 + (wid >> 1) * 64;
    const int s0 = blockIdx.x * 128 + (wid & 1) * 64;

    const int lr = lane & 15;
    const int lk = (lane >> 4) * 8;

    const unsigned short* Qb = QK + (size_t)b * SEQ * QK_N;
    const unsigned short* Kb = Qb + 256;

    float wv[4] = { w[0], w[1], w[2], w[3] };

    f32x4 fin[4][4];
#pragma unroll
    for (int i = 0; i < 4; ++i)
#pragma unroll
        for (int j = 0; j < 4; ++j) fin[i][j] = (f32x4)0.f;

    const unsigned short* qp = Qb + (size_t)(t0 + lr) * QK_N + lk;
    const unsigned short* kp = Kb + (size_t)(s0 + lr) * QK_N + lk;

#pragma unroll
    for (int h = 0; h < 4; ++h) {
        f32x4 acc[4][4];
#pragma unroll
        for (int i = 0; i < 4; ++i)
#pragma unroll
            for (int j = 0; j < 4; ++j) acc[i][j] = (f32x4)0.f;

#pragma unroll
        for (int ks = 0; ks < 2; ++ks) {
            bf16x8 a[4], bb[4];
#pragma unroll
            for (int i = 0; i < 4; ++i)
                a[i] = *reinterpret_cast<const bf16x8*>(
                    qp + (size_t)i * 16 * QK_N + h * 64 + ks * 32);
#pragma unroll
            for (int j = 0; j < 4; ++j)
                bb[j] = *reinterpret_cast<const bf16x8*>(
                    kp + (size_t)j * 16 * QK_N + ks * 32);
#pragma unroll
            for (int i = 0; i < 4; ++i)
#pragma unroll
                for (int j = 0; j < 4; ++j)
                    acc[i][j] = __builtin_amdgcn_mfma_f32_16x16x32_bf16(a[i], bb[j], acc[i][j], 0, 0, 0);
        }
#pragma unroll
        for (int i = 0; i < 4; ++i)
#pragma unroll
            for (int j = 0; j < 4; ++j)
#pragma unroll
                for (int r = 0; r < 4; ++r)
                    fin[i][j][r] += wv[h] * fmaxf(acc[i][j][r], 0.f);
    }

    const int orow = (lane >> 4) * 4;
    float* ob = out + (size_t)b * SEQ * SEQ;
#pragma unroll
    for (int i = 0; i < 4; ++i)
#pragma unroll
        for (int j = 0; j < 4; ++j)
#pragma unroll
            for (int r = 0; r < 4; ++r)
                ob[(size_t)(t0 + i * 16 + orow + r) * SEQ + s0 + j * 16 + lr] =
                    fin[i][j][r];
}

// ---------------- launch ----------------
extern "C" void kernel_launch(void* const* d_in, const int* in_sizes, int n_in,
                              void* d_out, int out_size, void* d_ws, size_t ws_size,
                              hipStream_t stream) {
    const float* h  = (const float*)d_in[0];   // [2,4096,2048]
    const float* Wq = (const float*)d_in[1];   // [256,2048]
    const float* Wk = (const float*)d_in[2];   // [64,2048]
    const float* w  = (const float*)d_in[3];   // [4]
    float* out = (float*)d_out;                // [2,4096,4096]

    unsigned short* W_swz = (unsigned short*)d_ws;                 // 32 chunks x 40KB = 1.25MB
    unsigned short* QKb   = (unsigned short*)((char*)d_ws + (size_t)NCHUNK * CHUNK_BYTES);

    cvt_w_swz<<<320, 256, 0, stream>>>(Wq, Wk, W_swz);
    proj_gemm<<<256, 512, 0, stream>>>(h, W_swz, QKb);
    scores_kernel<<<dim3(32, 32, 2), 256, 0, stream>>>(QKb, w, out);
}

// Round 4
// 111.642 us; speedup vs baseline: 1.4318x; 1.0146x over previous
//
#include <hip/hip_runtime.h>

// ---------------- types ----------------
typedef __attribute__((ext_vector_type(8))) short bf16x8;   // 8 bf16 in 4 VGPRs
typedef __attribute__((ext_vector_type(4))) float f32x4;
typedef __attribute__((ext_vector_type(8))) unsigned short us8;

#define K_DIM 2048
#define QK_N  320     // 256 q cols + 64 k cols
#define SEQ   4096
#define BK    64
#define NCHUNK 32                      // K_DIM / BK
#define NHALF  160                     // N columns per block
#define BM     64                      // M rows per block
#define BCHUNK 20480                   // bytes of one B chunk: 8 units * 160 cols * 16B

__device__ __forceinline__ unsigned short f2bf(float f) {
    unsigned int u = __builtin_bit_cast(unsigned int, f);
    u += 0x7FFFu + ((u >> 16) & 1u);      // round-to-nearest-even
    return (unsigned short)(u >> 16);
}

__device__ __forceinline__ void gld_lds16(const void* g, void* l) {
    __builtin_amdgcn_global_load_lds(
        (const __attribute__((address_space(1))) void*)g,
        (__attribute__((address_space(3))) void*)l,
        16, 0, 0);
}

// ---------------- W convert + re-layout ----------------
// ws layout: [2 N-halves][NCHUNK][8 k-units][160 cols][16B]
// (unit-major: ds_read_b128 of 16 consecutive cols at fixed k-unit is
// conflict-free; global_load_lds staging is a linear byte copy)
__global__ void cvt_w_swz(const float* __restrict__ Wq,
                          const float* __restrict__ Wk,
                          unsigned short* __restrict__ ws) {
    int id = blockIdx.x * 256 + threadIdx.x;   // 320*256 ids
    int c  = id >> 8;                          // 0..319 (output col)
    int k8 = id & 255;                         // 8-elem k group
    int k0 = k8 * 8;
    const float* src = (c < 256) ? (Wq + (size_t)c * K_DIM + k0)
                                 : (Wk + (size_t)(c - 256) * K_DIM + k0);
    float4 v0 = *reinterpret_cast<const float4*>(src);
    float4 v1 = *reinterpret_cast<const float4*>(src + 4);
    us8 o;
    o[0] = f2bf(v0.x); o[1] = f2bf(v0.y); o[2] = f2bf(v0.z); o[3] = f2bf(v0.w);
    o[4] = f2bf(v1.x); o[5] = f2bf(v1.y); o[6] = f2bf(v1.z); o[7] = f2bf(v1.w);
    int half = (c >= NHALF) ? 1 : 0;
    int cc   = c - half * NHALF;
    int kc = k0 / BK;            // chunk index 0..31
    int u  = (k0 % BK) >> 3;     // k-unit within chunk (0..7)
    size_t byteoff = (size_t)half * (NCHUNK * (size_t)BCHUNK)
                   + (size_t)kc * BCHUNK + ((size_t)(u * NHALF + cc) * 16);
    *reinterpret_cast<us8*>((char*)ws + byteoff) = o;
}

// ---------------- projection GEMM: C[8192][320] = h[8192][2048](fp32) * W^T ----
// grid (2 N-halves, 128 M-tiles) x 512 threads (8 waves: 4 rg x 2 cg).
// block tile 64x160; wave tile 16x80. Both operands double-buffered in LDS:
// A reg-staged (fp32 load -> cvt -> ds_write_b128, unit-major), B via
// global_load_lds from pre-swizzled W. Counted vmcnt keeps A prefetch in
// flight across barriers.
__global__ __launch_bounds__(512, 2) void proj_gemm(
    const float* __restrict__ A,            // h fp32 [8192][2048]
    const unsigned short* __restrict__ Wsz, // re-laid-out W
    unsigned short* __restrict__ C)         // [8192][320] bf16
{
    __shared__ unsigned short Asm[2][BM * BK];       // 2 x 8KB, [8 units][64 rows][8 bf16]
    __shared__ unsigned short Bsm[2][BCHUNK / 2];    // 2 x 20KB

    const int tid  = threadIdx.x;
    const int lane = tid & 63;
    const int wid  = tid >> 6;          // 0..7
    const int rg   = wid >> 1;          // 0..3 (M row-group)
    const int cg   = wid & 1;           // 0..1 (N col-group)
    const int mrow0 = blockIdx.y * BM;
    const int half  = blockIdx.x;
    const int lr = lane & 15, lg = lane >> 4;

    // A staging addressing: thread -> (row ar, k-unit au)
    const int ar = tid >> 3;            // 0..63
    const int au = tid & 7;             // 0..7
    const float* a_src = A + (size_t)(mrow0 + ar) * K_DIM + au * 8;
    const int a_dst_off = ((au << 6) + ar) << 4;     // byte offset in Asm[buf]

    const char* wsrc = (const char*)Wsz + (size_t)half * (NCHUNK * (size_t)BCHUNK)
                     + wid * 1024 + lane * 16;

    f32x4 acc[5];
#pragma unroll
    for (int j = 0; j < 5; ++j) acc[j] = (f32x4)0.f;

    auto stageB = [&](int kc, int buf) {
        const char* s = wsrc + (size_t)kc * BCHUNK;
        char* d = (char*)&Bsm[buf][0] + wid * 1024 + lane * 16;
        gld_lds16(s, d);
        gld_lds16(s + 8192, d + 8192);
        if (wid < 4) gld_lds16(s + 16384, d + 16384);   // wave-uniform branch
    };
    auto loadA = [&](int kc, float4& f0, float4& f1) {
        const float* p = a_src + (size_t)kc * BK;
        f0 = *reinterpret_cast<const float4*>(p);
        f1 = *reinterpret_cast<const float4*>(p + 4);
    };
    auto writeA = [&](float4 f0, float4 f1, int buf) {
        us8 o;
        o[0] = f2bf(f0.x); o[1] = f2bf(f0.y); o[2] = f2bf(f0.z); o[3] = f2bf(f0.w);
        o[4] = f2bf(f1.x); o[5] = f2bf(f1.y); o[6] = f2bf(f1.z); o[7] = f2bf(f1.w);
        *reinterpret_cast<us8*>((char*)&Asm[buf][0] + a_dst_off) = o;
    };
    auto compute = [&](int buf) {
        const char* ab = (const char*)&Asm[buf][0];
        const char* bb = (const char*)&Bsm[buf][0];
#pragma unroll
        for (int ks = 0; ks < 2; ++ks) {
            const int u = ks * 4 + lg;
            bf16x8 a = *reinterpret_cast<const bf16x8*>(
                ab + (((u << 6) + rg * 16 + lr) << 4));
            const char* bu = bb + (size_t)u * (NHALF * 16);
#pragma unroll
            for (int j = 0; j < 5; ++j) {
                bf16x8 b = *reinterpret_cast<const bf16x8*>(
                    bu + ((cg * 80 + j * 16 + lr) << 4));
                acc[j] = __builtin_amdgcn_mfma_f32_16x16x32_bf16(a, b, acc[j], 0, 0, 0);
            }
        }
    };

#define WAIT_BAR(N) do { \
        asm volatile("s_waitcnt vmcnt(" #N ") lgkmcnt(0)" ::: "memory"); \
        __builtin_amdgcn_s_barrier(); \
    } while (0)

    float4 r0a, r0b;   // A-regs parity 0
    float4 r1a, r1b;   // A-regs parity 1

    // prologue: chunk 0 into buf0, A(1) regs in flight
    stageB(0, 0);
    loadA(0, r0a, r0b);
    asm volatile("s_waitcnt vmcnt(0)" ::: "memory");
    writeA(r0a, r0b, 0);
    loadA(1, r1a, r1b);
    asm volatile("s_waitcnt lgkmcnt(0)" ::: "memory");
    __builtin_amdgcn_s_barrier();

    // main loop, hand-unrolled x2 (t even). chunk t lives in buf t&1.
    for (int t = 0; t < NCHUNK; t += 2) {
        // ---- half 1: compute chunk t (buf0) ----
        stageB(t + 1, 1);
        {
            int kc = (t + 2 < NCHUNK) ? t + 2 : NCHUNK - 1;
            loadA(kc, r0a, r0b);          // A(t+2) -> parity 0
        }
        compute(0);
        writeA(r1a, r1b, 1);              // A(t+1) -> buf1
        WAIT_BAR(2);
        // ---- half 2: compute chunk t+1 (buf1) ----
        const int u = t + 1;
        if (u < NCHUNK - 1) {
            stageB(u + 1, 0);
            int kc = (u + 2 < NCHUNK) ? u + 2 : NCHUNK - 1;
            loadA(kc, r1a, r1b);          // A(u+2) -> parity 1
        }
        compute(1);
        if (u < NCHUNK - 1) {
            writeA(r0a, r0b, 0);          // A(u+1) -> buf0
            WAIT_BAR(2);
        }
    }
#undef WAIT_BAR

    // epilogue: C layout col=lane&15, row=(lane>>4)*4+r
    const int crow = mrow0 + rg * 16 + lg * 4;
    const int ccol = half * NHALF + cg * 80 + lr;
#pragma unroll
    for (int j = 0; j < 5; ++j)
#pragma unroll
        for (int r = 0; r < 4; ++r)
            C[(size_t)(crow + r) * QK_N + ccol + j * 16] = f2bf(acc[j][r]);
}

// ---------------- scores: I[b,t,s] = sum_h w[h]*relu(Q_h K^T) ----------------
// grid (32,32,2); block 256 = 4 waves (2x2). block tile 128x128, wave tile 64x64.
// MFMA operands swapped (a=K-frag, b=Q-frag) so each lane's 4 acc regs are 4
// consecutive s values -> float4 stores.
__global__ __launch_bounds__(256) void scores_kernel(
    const unsigned short* __restrict__ QK,   // [B][4096][320] bf16
    const float* __restrict__ w,             // [4]
    float* __restrict__ out)                 // [B][4096][4096] fp32
{
    const int lane = threadIdx.x & 63;
    const int wid  = threadIdx.x >> 6;
    const int b  = blockIdx.z;
    const int t0 = blockIdx.y * 128 + (wid >> 1) * 64;
    const int s0 = blockIdx.x * 128 + (wid & 1) * 64;

    const int lr = lane & 15;
    const int lk = (lane >> 4) * 8;
    const int lg = lane >> 4;

    const unsigned short* Qb = QK + (size_t)b * SEQ * QK_N;
    const unsigned short* Kb = Qb + 256;

    float wv[4] = { w[0], w[1], w[2], w[3] };

    f32x4 fin[4][4];
#pragma unroll
    for (int i = 0; i < 4; ++i)
#pragma unroll
        for (int j = 0; j < 4; ++j) fin[i][j] = (f32x4)0.f;

    const unsigned short* qp = Qb + (size_t)(t0 + lr) * QK_N + lk;
    const unsigned short* kp = Kb + (size_t)(s0 + lr) * QK_N + lk;

#pragma unroll
    for (int h = 0; h < 4; ++h) {
        f32x4 acc[4][4];
#pragma unroll
        for (int i = 0; i < 4; ++i)
#pragma unroll
            for (int j = 0; j < 4; ++j) acc[i][j] = (f32x4)0.f;

#pragma unroll
        for (int ks = 0; ks < 2; ++ks) {
            bf16x8 qf[4], kf[4];
#pragma unroll
            for (int i = 0; i < 4; ++i)
                qf[i] = *reinterpret_cast<const bf16x8*>(
                    qp + (size_t)i * 16 * QK_N + h * 64 + ks * 32);
#pragma unroll
            for (int j = 0; j < 4; ++j)
                kf[j] = *reinterpret_cast<const bf16x8*>(
                    kp + (size_t)j * 16 * QK_N + ks * 32);
            // swapped: a=K (s in reg dim), b=Q (t on lane&15)
#pragma unroll
            for (int i = 0; i < 4; ++i)
#pragma unroll
                for (int j = 0; j < 4; ++j)
                    acc[i][j] = __builtin_amdgcn_mfma_f32_16x16x32_bf16(kf[j], qf[i], acc[i][j], 0, 0, 0);
        }
#pragma unroll
        for (int i = 0; i < 4; ++i)
#pragma unroll
            for (int j = 0; j < 4; ++j)
#pragma unroll
                for (int r = 0; r < 4; ++r)
                    fin[i][j][r] += wv[h] * fmaxf(acc[i][j][r], 0.f);
    }

    // store: lane holds t = t0+i*16+lr, s = s0+j*16+lg*4 .. +3 (contiguous)
    float* ob = out + (size_t)b * SEQ * SEQ;
#pragma unroll
    for (int i = 0; i < 4; ++i) {
        const size_t rbase = (size_t)(t0 + i * 16 + lr) * SEQ + s0 + lg * 4;
#pragma unroll
        for (int j = 0; j < 4; ++j) {
            float4 v;
            v.x = fin[i][j][0]; v.y = fin[i][j][1];
            v.z = fin[i][j][2]; v.w = fin[i][j][3];
            *reinterpret_cast<float4*>(&ob[rbase + j * 16]) = v;
        }
    }
}

// ---------------- launch ----------------
extern "C" void kernel_launch(void* const* d_in, const int* in_sizes, int n_in,
                              void* d_out, int out_size, void* d_ws, size_t ws_size,
                              hipStream_t stream) {
    const float* h  = (const float*)d_in[0];   // [2,4096,2048]
    const float* Wq = (const float*)d_in[1];   // [256,2048]
    const float* Wk = (const float*)d_in[2];   // [64,2048]
    const float* w  = (const float*)d_in[3];   // [4]
    float* out = (float*)d_out;                // [2,4096,4096]

    unsigned short* W_swz = (unsigned short*)d_ws;                 // 2 x 32 x 20KB = 1.25MB
    unsigned short* QKb   = (unsigned short*)((char*)d_ws + 2 * (size_t)NCHUNK * BCHUNK);

    cvt_w_swz<<<320, 256, 0, stream>>>(Wq, Wk, W_swz);
    proj_gemm<<<dim3(2, 128), 512, 0, stream>>>(h, W_swz, QKb);
    scores_kernel<<<dim3(32, 32, 2), 256, 0, stream>>>(QKb, w, out);
}